// Round 8
// baseline (599.353 us; speedup 1.0000x reference)
//
#include <hip/hip_runtime.h>
#include <stdint.h>
#include <math.h>

typedef __attribute__((ext_vector_type(8))) short s16x8;
typedef __attribute__((ext_vector_type(4))) short s16x4;
typedef __attribute__((ext_vector_type(4))) float f32x4;

#define NEGH (-1.0e30f)

__device__ __forceinline__ short f2bf(float f) {
  union { float f; unsigned int i; } c; c.f = f;
  unsigned int lsb = (c.i >> 16) & 1u;
  c.i += 0x7fffu + lsb;
  return (short)(c.i >> 16);
}
__device__ __forceinline__ float bf2f(short u) {
  union { unsigned int i; float f; } c;
  c.i = ((unsigned int)(unsigned short)u) << 16;
  return c.f;
}

// async global->LDS, 16B per lane. LDS dest must be wave-uniform base + lane*16.
#define GLOAD_LDS16(gp, lp)                                                  \
  __builtin_amdgcn_global_load_lds(                                          \
      (__attribute__((address_space(1))) void*)(void*)(gp),                  \
      (__attribute__((address_space(3))) void*)(lp), 16, 0, 0)

// ---------------------------------------------------------------------------
// fp32 -> bf16 conversion, 4 elements/thread. n must be divisible by 1024.
// ---------------------------------------------------------------------------
__global__ __launch_bounds__(256) void cvt_kernel(const float* __restrict__ in,
                                                  short* __restrict__ out)
{
  const size_t i = ((size_t)blockIdx.x * 256 + threadIdx.x) * 4;
  const float4 v = *(const float4*)(in + i);
  s16x4 o = { f2bf(v.x), f2bf(v.y), f2bf(v.z), f2bf(v.w) };
  *(s16x4*)(out + i) = o;
}

// ---------------------------------------------------------------------------
// Merged weight conversions + rope table (saves 3 launches):
// blocks [0,4096) wq; [4096,5120) wk; [5120,6144) wv; [6144,6656) rope tab.
// ---------------------------------------------------------------------------
__global__ __launch_bounds__(256) void wcvt_kernel(
    const float* __restrict__ wq, const float* __restrict__ wk,
    const float* __restrict__ wv, short* __restrict__ wqb,
    short* __restrict__ wkb, short* __restrict__ wvb,
    float2* __restrict__ tab)
{
  const int bid = blockIdx.x;
  if (bid < 6144) {
    const float* in; short* out; int lb;
    if (bid < 4096)      { in = wq; out = wqb; lb = bid; }
    else if (bid < 5120) { in = wk; out = wkb; lb = bid - 4096; }
    else                 { in = wv; out = wvb; lb = bid - 5120; }
    const size_t i = ((size_t)lb * 256 + threadIdx.x) * 4;
    const float4 v = *(const float4*)(in + i);
    s16x4 o = { f2bf(v.x), f2bf(v.y), f2bf(v.z), f2bf(v.w) };
    *(s16x4*)(out + i) = o;
  } else {
    const int i = (bid - 6144) * 256 + threadIdx.x;   // 131072
    const int d = i & 63;
    const float fr = (float)(i >> 6) * exp2f((float)d * -0.20762050593048584f);
    float sn, cs;
    sincosf(fr, &sn, &cs);
    tab[i] = make_float2(cs, sn);
  }
}

// ---------------------------------------------------------------------------
// GEMM (small-N): C[M,N] = A[M,K] * W[N,K]^T + bias[N]. 128x128 tile, BK=64,
// 256 threads. omode: 0 = bf16 C row-major; 1 = fp32 C row-major;
// 3 = split KV: n<512 -> bf16 C[m*512+n] (bias), n>=512 -> bf16 C2[m*512+n-512]
//     (bias2). XCD remap for grid 8x64 (KV call).
// ---------------------------------------------------------------------------
__global__ __launch_bounds__(256) void gemm_bt(
    const short* __restrict__ A, const short* __restrict__ W,
    const float* __restrict__ bias, const float* __restrict__ bias2,
    void* __restrict__ C, void* __restrict__ C2,
    int M, int N, int K, int omode)
{
  __shared__ __align__(16) short As[128 * 64];
  __shared__ __align__(16) short Bs[128 * 64];

  const int t = threadIdx.x;
  const int l = t & 63;
  const int w = t >> 6;
  const int lane16 = l & 15;
  const int quad = l >> 4;
  const int wm = w >> 1, wn = w & 1;

  int bx = blockIdx.x, by = blockIdx.y;
  if (gridDim.x == 8 && gridDim.y == 64) {       // KV call: XCD-aware remap
    const int lid = blockIdx.x + 8 * blockIdx.y; // 0..511, x fastest
    const int xcd = lid & 7, idx = lid >> 3;     // idx 0..63
    by = xcd * 8 + (idx >> 3);                   // 0..63
    bx = idx & 7;                                // 0..7
  }
  const int mb0 = by * 128;
  const int nb0 = bx * 128;

  const f32x4 zero = {0.f, 0.f, 0.f, 0.f};
  f32x4 acc[4][4];
#pragma unroll
  for (int i = 0; i < 4; ++i)
#pragma unroll
    for (int j = 0; j < 4; ++j) acc[i][j] = zero;

  const int sr = t >> 3;
  const int sp = t & 7;
  const short* Ag = A + (size_t)(mb0 + sr) * K + sp * 8;
  const short* Wg = W + (size_t)(nb0 + sr) * K + sp * 8;
  short* Al = As + t * 8;
  short* Bl = Bs + t * 8;

  const int nkt = K >> 6;
  for (int kt = 0; kt < nkt; ++kt) {
    __syncthreads();
    const int kof = kt * 64;
#pragma unroll
    for (int it = 0; it < 4; ++it) {
      GLOAD_LDS16(Ag + kof + (size_t)(it * 32) * K, Al + it * 2048);
      GLOAD_LDS16(Wg + kof + (size_t)(it * 32) * K, Bl + it * 2048);
    }
    __syncthreads();
#pragma unroll
    for (int kk = 0; kk < 2; ++kk) {
      s16x8 af[4], bf[4];
#pragma unroll
      for (int mi = 0; mi < 4; ++mi)
        af[mi] = *(const s16x8*)&As[(wm * 64 + mi * 16 + lane16) * 64 +
                                    kk * 32 + quad * 8];
#pragma unroll
      for (int ni = 0; ni < 4; ++ni)
        bf[ni] = *(const s16x8*)&Bs[(wn * 64 + ni * 16 + lane16) * 64 +
                                    kk * 32 + quad * 8];
#pragma unroll
      for (int mi = 0; mi < 4; ++mi)
#pragma unroll
        for (int ni = 0; ni < 4; ++ni)
          acc[mi][ni] = __builtin_amdgcn_mfma_f32_16x16x32_bf16(
              af[mi], bf[ni], acc[mi][ni], 0, 0, 0);
    }
  }

#pragma unroll
  for (int ni = 0; ni < 4; ++ni) {
    const int n = nb0 + wn * 64 + ni * 16 + lane16;
    const float bvx = (omode == 3 && n >= 512) ? bias2[n - 512] : bias[n];
#pragma unroll
    for (int mi = 0; mi < 4; ++mi) {
      const int m0 = mb0 + wm * 64 + mi * 16 + quad * 4;
#pragma unroll
      for (int r = 0; r < 4; ++r) {
        const int m = m0 + r;
        const float v = acc[mi][ni][r] + bvx;
        if (omode == 0) {
          ((short*)C)[(size_t)m * N + n] = f2bf(v);
        } else if (omode == 1) {
          ((float*)C)[(size_t)m * N + n] = v;
        } else {
          if (n < 512) ((short*)C)[(size_t)m * 512 + n] = f2bf(v);
          else         ((short*)C2)[(size_t)m * 512 + (n - 512)] = f2bf(v);
        }
      }
    }
  }
}

// ---------------------------------------------------------------------------
// GEMM (big): 256x256 tile, BK=64, 512 threads = 8 waves (2M x 4N), 8-phase
// schedule (T2+T3+T4+T5), counted vmcnt(6) at P4/P8 only (r7 ledger).
// XCD remap for grid 8x32. omode: 0 = bf16 C; 1 = fp32 C.
// ---------------------------------------------------------------------------
__global__ __launch_bounds__(512, 2) void gemm256_bt(
    const short* __restrict__ A, const short* __restrict__ W,
    const float* __restrict__ bias, void* __restrict__ C,
    int M, int N, int K, int omode)
{
  __shared__ __align__(16) short Asm[2 * 16384];   // [buf][kk][row][32]
  __shared__ __align__(16) short Bsm[2 * 16384];

  const int t = threadIdx.x;
  const int l = t & 63;
  const int w = t >> 6;                // 0..7
  const int lane16 = l & 15;
  const int quad = l >> 4;
  const int wm = w >> 2;               // 0..1
  const int wn = w & 3;                // 0..3

  int bx = blockIdx.x, by = blockIdx.y;
  if (gridDim.x == 8 && gridDim.y == 32) {
    const int bid = blockIdx.y * 8 + blockIdx.x;   // 0..255, x fastest
    const int xcd = bid & 7, idx = bid >> 3;       // idx 0..31
    const int xc = xcd & 3, yc = xcd >> 2;         // 4 x-chunks x 2 y-chunks
    bx = xc * 2 + (idx & 1);                       // 0..7
    by = yc * 16 + (idx >> 1);                     // 0..31
  }
  const int mb0 = by * 256;
  const int nb0 = bx * 256;

  const f32x4 zero = {0.f, 0.f, 0.f, 0.f};
  f32x4 acc[8][4];
#pragma unroll
  for (int i = 0; i < 8; ++i)
#pragma unroll
    for (int j = 0; j < 4; ++j) acc[i][j] = zero;

  const int srow = t >> 2;                       // 0..127
  const int scs = (t & 3) ^ ((t >> 3) & 3);      // pre-swizzled source chunk
  const short* Ag = A + (size_t)(mb0 + srow) * K + scs * 8;
  const short* Wg = W + (size_t)(nb0 + srow) * K + scs * 8;
  const size_t rstep = (size_t)128 * K;

#define STAGE_A(b, kt, kh)                                                    \
  do {                                                                        \
    const size_t ko_ = (size_t)(kt) * 64 + (kh) * 32;                         \
    GLOAD_LDS16(Ag + ko_,         Asm + (b) * 16384 + (kh) * 8192 + t * 8);   \
    GLOAD_LDS16(Ag + ko_ + rstep, Asm + (b) * 16384 + (kh) * 8192 + 4096 + t * 8); \
  } while (0)
#define STAGE_B(b, kt, kh)                                                    \
  do {                                                                        \
    const size_t ko_ = (size_t)(kt) * 64 + (kh) * 32;                         \
    GLOAD_LDS16(Wg + ko_,         Bsm + (b) * 16384 + (kh) * 8192 + t * 8);   \
    GLOAD_LDS16(Wg + ko_ + rstep, Bsm + (b) * 16384 + (kh) * 8192 + 4096 + t * 8); \
  } while (0)

#define VMW6                                                                  \
  asm volatile("s_waitcnt vmcnt(6)" ::: "memory");                            \
  __builtin_amdgcn_sched_barrier(0);

  s16x8 bfr[4];

#define DO_PHASE(BUF, KK, MG, READB, STAGE_STMT, VM_STMT)                     \
  {                                                                           \
    const short* Abase = Asm + (BUF) * 16384 + (KK) * 8192;                   \
    const short* Bbase = Bsm + (BUF) * 16384 + (KK) * 8192;                   \
    if (READB) {                                                              \
      _Pragma("unroll")                                                       \
      for (int ni = 0; ni < 4; ++ni) {                                        \
        const int nr = wn * 64 + ni * 16 + lane16;                            \
        bfr[ni] = *(const s16x8*)(Bbase + nr * 32 +                           \
                                  ((quad ^ ((nr >> 1) & 3)) << 3));           \
      }                                                                       \
    }                                                                         \
    s16x8 afr[4];                                                             \
    _Pragma("unroll")                                                         \
    for (int mi2 = 0; mi2 < 4; ++mi2) {                                       \
      const int mr = wm * 128 + (MG) * 64 + mi2 * 16 + lane16;                \
      afr[mi2] = *(const s16x8*)(Abase + mr * 32 +                            \
                                 ((quad ^ ((mr >> 1) & 3)) << 3));            \
    }                                                                         \
    STAGE_STMT;                                                               \
    __builtin_amdgcn_s_barrier();                                             \
    asm volatile("s_waitcnt lgkmcnt(0)" ::: "memory");                        \
    __builtin_amdgcn_sched_barrier(0);                                        \
    __builtin_amdgcn_s_setprio(1);                                            \
    _Pragma("unroll")                                                         \
    for (int mi2 = 0; mi2 < 4; ++mi2)                                         \
      _Pragma("unroll")                                                       \
      for (int ni = 0; ni < 4; ++ni)                                          \
        acc[(MG) * 4 + mi2][ni] = __builtin_amdgcn_mfma_f32_16x16x32_bf16(    \
            afr[mi2], bfr[ni], acc[(MG) * 4 + mi2][ni], 0, 0, 0);             \
    __builtin_amdgcn_s_setprio(0);                                            \
    VM_STMT                                                                   \
    __builtin_amdgcn_s_barrier();                                             \
  }

  const int NT = K >> 6;               // K-tiles (even; >= 2)

  // prologue: 7 stages (14 loads); wait until buf0 (loads 1-8) landed.
  STAGE_B(0, 0, 0); STAGE_A(0, 0, 0); STAGE_B(0, 0, 1); STAGE_A(0, 0, 1);
  STAGE_B(1, 1, 0); STAGE_A(1, 1, 0); STAGE_B(1, 1, 1);
  asm volatile("s_waitcnt vmcnt(6)" ::: "memory");
  __builtin_amdgcn_sched_barrier(0);
  __builtin_amdgcn_s_barrier();

  for (int i2 = 0; i2 < NT; i2 += 2) {
    const int tp1 = (i2 + 1 < NT) ? i2 + 1 : NT - 1;
    const int tp2 = (i2 + 2 < NT) ? i2 + 2 : NT - 1;
    const int tp3 = (i2 + 3 < NT) ? i2 + 3 : NT - 1;
    DO_PHASE(0, 0, 0, true,  STAGE_A(1, tp1, 1), )        // P1
    DO_PHASE(0, 0, 1, false, STAGE_B(0, tp2, 0), )        // P2
    DO_PHASE(0, 1, 0, true,  STAGE_A(0, tp2, 0), )        // P3
    DO_PHASE(0, 1, 1, false, STAGE_B(0, tp2, 1), VMW6)    // P4
    DO_PHASE(1, 0, 0, true,  STAGE_A(0, tp2, 1), )        // P5
    DO_PHASE(1, 0, 1, false, STAGE_B(1, tp3, 0), )        // P6
    DO_PHASE(1, 1, 0, true,  STAGE_A(1, tp3, 0), )        // P7
    DO_PHASE(1, 1, 1, false, STAGE_B(1, tp3, 1), VMW6)    // P8
  }

#pragma unroll
  for (int ni = 0; ni < 4; ++ni) {
    const int n = nb0 + wn * 64 + ni * 16 + lane16;
    const float bv = bias[n];
#pragma unroll
    for (int mi = 0; mi < 8; ++mi) {
      const int m0 = mb0 + wm * 128 + mi * 16 + quad * 4;
#pragma unroll
      for (int r = 0; r < 4; ++r) {
        const float v = acc[mi][ni][r] + bv;
        if (omode == 0) ((short*)C)[(size_t)(m0 + r) * N + n] = f2bf(v);
        else            ((float*)C)[(size_t)(m0 + r) * N + n] = v;
      }
    }
  }
#undef DO_PHASE
#undef STAGE_A
#undef STAGE_B
#undef VMW6
}

// ---------------------------------------------------------------------------
// RoPE in place on bf16 buf[row][head*128 + d], pairs (d, d+64), pos = row%2048.
// (K only; Q-rope is fused into attn.)
// ---------------------------------------------------------------------------
__global__ __launch_bounds__(256) void rope_kernel(short* __restrict__ buf,
                                                   int lognh,
                                                   const float2* __restrict__ tab)
{
  const int idx = blockIdx.x * 256 + threadIdx.x;
  const int d = idx & 63;
  const int rest = idx >> 6;            // row*nh + h
  const int row = rest >> lognh;
  const int pos = row & 2047;
  const float2 cssn = tab[(pos << 6) | d];
  const float cs = cssn.x, sn = cssn.y;
  const size_t base = (size_t)rest * 128 + d;
  const float lo = bf2f(buf[base]);
  const float hi = bf2f(buf[base + 64]);
  buf[base]      = f2bf(lo * cs - hi * sn);
  buf[base + 64] = f2bf(hi * cs + lo * sn);
}

// ---------------------------------------------------------------------------
// Transpose V: in[m=b*2048+s][n(512)] -> out[(b*512+n)*2048 + s]. 64x64 LDS
// tiles, coalesced 16B on both sides. grid (128, 8), 256 threads.
// ---------------------------------------------------------------------------
__global__ __launch_bounds__(256) void trans_kernel(const short* __restrict__ in,
                                                    short* __restrict__ out)
{
  __shared__ short T[64 * 72];
  const int t = threadIdx.x;
  const int ms = blockIdx.x * 64;   // global m (= b*2048 + s) tile base
  const int ns = blockIdx.y * 64;   // n tile base
  const int b = ms >> 11;
  const int sl = ms & 2047;
  const int r = t >> 3, sg = t & 7;
#pragma unroll
  for (int j = 0; j < 2; ++j) {
    const uint4 v = *(const uint4*)(in + (size_t)(ms + r + 32 * j) * 512 + ns + sg * 8);
    *(uint4*)&T[(r + 32 * j) * 72 + sg * 8] = v;
  }
  __syncthreads();
#pragma unroll
  for (int j = 0; j < 2; ++j) {
    const int nr = r + 32 * j;
    s16x8 v;
#pragma unroll
    for (int i = 0; i < 8; ++i) v[i] = T[(sg * 8 + i) * 72 + nr];
    *(s16x8*)(out + ((size_t)(b * 512 + ns + nr)) * 2048 + sl + sg * 8) = v;
  }
}

// ---------------------------------------------------------------------------
// Flash attention, causal, GQA. r8: 4 waves x 32 q-rows each (2x16 substrips)
// -- each K/V LDS fragment read now feeds TWO MFMAs, halving the LDS-read
// amplification that r7 analysis identified as the limiter (16 waves x 32KB
// per 128-row tile-step -> 8 waves x 32KB for the same work). Same 128-row
// strips, strip pairing, double-buffered K/V, one barrier/tile, fused Q-RoPE,
// XCD remap as r6/r7. In-place og==qg safe.
// ---------------------------------------------------------------------------
__global__ __launch_bounds__(256, 2) void attn_kernel(
    const short* __restrict__ qg, const short* __restrict__ kg,
    const short* __restrict__ vtg, short* __restrict__ og,
    const float2* __restrict__ tab)
{
  __shared__ __align__(16) short Ksm[2 * 64 * 128];   // [buf][key][d], swizzled
  __shared__ __align__(16) short Vsm[2 * 128 * 64];   // [buf][d][key], swizzled
  __shared__ __align__(16) short Psm[128 * 64];       // [q][key], wave-private rows

  const int t = threadIdx.x;
  const int l = t & 63;
  const int w = t >> 6;                 // 0..3
  const int lane16 = l & 15;
  const int quad = l >> 4;

  // XCD remap: lid 0..511; group g = (b,kv) 0..15; two groups per XCD.
  const int lid = blockIdx.x + 8 * (blockIdx.y + 16 * blockIdx.z);
  const int xcd = lid & 7, idx = lid >> 3;        // idx 0..63
  const int g = xcd * 2 + (idx >> 5);             // 0..15
  const int wv_ = idx & 31;
  const int b = g >> 2, kv = g & 3;
  const int h = kv * 4 + (wv_ >> 3);
  const int jb = wv_ & 7;

  // staging geometry (256 threads, 4 issues each of K and V):
  // K tile 64x128: issue j covers rows j*16 + (t>>4), 16B seg t&15
  // V tile 128x64: issue j covers rows j*32 + (t>>3), 16B seg t&7
  const int krow = t >> 4, kseg = t & 15;
  const int vrow = t >> 3, vseg = t & 7;
  const int kswz = (kseg ^ (krow & 7)) * 8;   // (row&7) invariant across issues
  const int vswz = (vseg ^ (vrow & 7)) * 8;

  const short* kbaseptr = kg + ((size_t)(b * 2048)) * 512 + kv * 128;
  const short* vbaseptr = vtg + ((size_t)(b * 512 + kv * 128)) * 2048;

  const float SC = 0.08838834764831845f * 1.4426950408889634f; // rsqrt(128)*log2e
  const f32x4 zero = {0.f, 0.f, 0.f, 0.f};
  const int swz = (lane16 & 7) << 3;

  uint4 kr[4], vr[4];
#define LOADT()                                                               \
  do {                                                                        \
    kr[0] = *(const uint4*)kld;                                               \
    kr[1] = *(const uint4*)(kld + 16 * 512);                                  \
    kr[2] = *(const uint4*)(kld + 32 * 512);                                  \
    kr[3] = *(const uint4*)(kld + 48 * 512);                                  \
    vr[0] = *(const uint4*)vld;                                               \
    vr[1] = *(const uint4*)(vld + 32 * 2048);                                 \
    vr[2] = *(const uint4*)(vld + 64 * 2048);                                 \
    vr[3] = *(const uint4*)(vld + 96 * 2048);                                 \
    kld += 64 * 512;                                                          \
    vld += 64;                                                                \
  } while (0)
#define WRITET(c)                                                             \
  do {                                                                        \
    *(uint4*)&Ksm[(c) * 8192 + krow * 128 + kswz] = kr[0];                    \
    *(uint4*)&Ksm[(c) * 8192 + (16 + krow) * 128 + kswz] = kr[1];             \
    *(uint4*)&Ksm[(c) * 8192 + (32 + krow) * 128 + kswz] = kr[2];             \
    *(uint4*)&Ksm[(c) * 8192 + (48 + krow) * 128 + kswz] = kr[3];             \
    *(uint4*)&Vsm[(c) * 8192 + vrow * 64 + vswz] = vr[0];                     \
    *(uint4*)&Vsm[(c) * 8192 + (32 + vrow) * 64 + vswz] = vr[1];              \
    *(uint4*)&Vsm[(c) * 8192 + (64 + vrow) * 64 + vswz] = vr[2];              \
    *(uint4*)&Vsm[(c) * 8192 + (96 + vrow) * 64 + vswz] = vr[3];              \
  } while (0)

  for (int sp2 = 0; sp2 < 2; ++sp2) {
    const int jj = sp2 ? (15 - jb) : jb;
    const int qb0 = jj * 128;
    const int qw0 = qb0 + w * 32;       // wave owns 32 q rows
    const int qmaxw = qw0 + 31;
    const int ntl = 2 * jj + 2;

    // staging pointers for this strip (advance per staged tile)
    const short* kld = kbaseptr + (size_t)krow * 512 + kseg * 8;
    const short* vld = vbaseptr + (size_t)vrow * 2048 + vseg * 8;

    // Q fragments with FUSED RoPE, per substrip s: rows qw0 + s*16 + lane16.
    s16x8 qf[2][4];
#pragma unroll
    for (int s = 0; s < 2; ++s) {
      const short* qrow =
          qg + ((size_t)(b * 2048 + qw0 + s * 16 + lane16)) * 2048 + h * 128 + quad * 8;
      s16x8 qr[4];
#pragma unroll
      for (int kk = 0; kk < 4; ++kk) qr[kk] = *(const s16x8*)(qrow + kk * 32);
      const float2* tb = tab + (((size_t)(qw0 + s * 16 + lane16)) << 6) + quad * 8;
#pragma unroll
      for (int kk = 0; kk < 2; ++kk) {
        float lo[8], hi[8];
#pragma unroll
        for (int j = 0; j < 8; ++j) {
          const float2 cs2 = tb[kk * 32 + j];
          const float l0 = bf2f(qr[kk][j]);
          const float h0 = bf2f(qr[kk + 2][j]);
          lo[j] = l0 * cs2.x - h0 * cs2.y;
          hi[j] = h0 * cs2.x + l0 * cs2.y;
        }
        union { unsigned int u[4]; s16x8 v; } plo, phi;
#pragma unroll
        for (int j = 0; j < 4; ++j) {
          asm("v_cvt_pk_bf16_f32 %0, %1, %2"
              : "=v"(plo.u[j]) : "v"(lo[2 * j]), "v"(lo[2 * j + 1]));
          asm("v_cvt_pk_bf16_f32 %0, %1, %2"
              : "=v"(phi.u[j]) : "v"(hi[2 * j]), "v"(hi[2 * j + 1]));
        }
        qf[s][kk] = plo.v;
        qf[s][kk + 2] = phi.v;
      }
    }

    f32x4 o[2][8];
#pragma unroll
    for (int s = 0; s < 2; ++s)
#pragma unroll
      for (int i = 0; i < 8; ++i) o[s][i] = zero;
    float m_i[2] = {NEGH, NEGH};
    float l_i[2] = {0.f, 0.f};

    // prologue: stage tile 0 into buf 0
    LOADT();
    WRITET(0);
    __syncthreads();
    int cur = 0;

    for (int tl = 0; tl < ntl; ++tl) {
      const int kbase = tl * 64;
      if (tl + 1 < ntl) LOADT();        // issue; flies under compute

      if (kbase <= qmaxw) {
        const short* Kb = Ksm + cur * 8192;
        const short* Vb = Vsm + cur * 8192;
        f32x4 st[2][4];
#pragma unroll
        for (int s = 0; s < 2; ++s)
#pragma unroll
          for (int mt = 0; mt < 4; ++mt) st[s][mt] = zero;
        // QK: each K a-frag feeds both substrips (2 MFMAs per LDS read)
        __builtin_amdgcn_s_setprio(1);
#pragma unroll
        for (int mt = 0; mt < 4; ++mt) {
          const int rb = (mt * 16 + lane16) * 128;
#pragma unroll
          for (int kk = 0; kk < 4; ++kk) {
            const s16x8 a = *(const s16x8*)&Kb[rb + ((kk * 32 + quad * 8) ^ swz)];
            st[0][mt] = __builtin_amdgcn_mfma_f32_16x16x32_bf16(a, qf[0][kk], st[0][mt], 0, 0, 0);
            st[1][mt] = __builtin_amdgcn_mfma_f32_16x16x32_bf16(a, qf[1][kk], st[1][mt], 0, 0, 0);
          }
        }
        __builtin_amdgcn_s_setprio(0);

        // ---- softmax on raw st per substrip ----
        const bool maskt = (kbase + 63 > qw0);
#pragma unroll
        for (int s = 0; s < 2; ++s) {
          const int qabs = qw0 + s * 16 + lane16;
          if (maskt) {
#pragma unroll
            for (int mt = 0; mt < 4; ++mt)
#pragma unroll
              for (int r = 0; r < 4; ++r) {
                if ((kbase + mt * 16 + quad * 4 + r) > qabs) st[s][mt][r] = NEGH;
              }
          }
          float tm[4];
#pragma unroll
          for (int mt = 0; mt < 4; ++mt)
            tm[mt] = fmaxf(fmaxf(st[s][mt][0], st[s][mt][1]),
                           fmaxf(st[s][mt][2], st[s][mt][3]));
          float tl_ = fmaxf(fmaxf(tm[0], tm[1]), fmaxf(tm[2], tm[3]));
          tl_ = fmaxf(tl_, __shfl_xor(tl_, 16));
          tl_ = fmaxf(tl_, __shfl_xor(tl_, 32));
          const float mnew = fmaxf(m_i[s], tl_);
          if (!__all(tl_ <= m_i[s])) {
            const float alpha = exp2f((m_i[s] - mnew) * SC);
            l_i[s] *= alpha;
#pragma unroll
            for (int r = 0; r < 4; ++r) {
              const float ar = __shfl(alpha, quad * 4 + r);
#pragma unroll
              for (int ntd = 0; ntd < 8; ++ntd) o[s][ntd][r] *= ar;
            }
          }
          m_i[s] = mnew;
          const float mS = mnew * SC;
          float rs = 0.f;
#pragma unroll
          for (int mt = 0; mt < 4; ++mt) {
            const float p0 = exp2f(fmaf(st[s][mt][0], SC, -mS));
            const float p1 = exp2f(fmaf(st[s][mt][1], SC, -mS));
            const float p2 = exp2f(fmaf(st[s][mt][2], SC, -mS));
            const float p3 = exp2f(fmaf(st[s][mt][3], SC, -mS));
            rs += (p0 + p1) + (p2 + p3);
            uint2 pk2;
            asm("v_cvt_pk_bf16_f32 %0, %1, %2" : "=v"(pk2.x) : "v"(p0), "v"(p1));
            asm("v_cvt_pk_bf16_f32 %0, %1, %2" : "=v"(pk2.y) : "v"(p2), "v"(p3));
            *(uint2*)&Psm[(w * 32 + s * 16 + lane16) * 64 +
                          ((mt * 16 + quad * 4) ^ swz)] = pk2;
          }
          rs += __shfl_xor(rs, 16);
          rs += __shfl_xor(rs, 32);
          l_i[s] += rs;
        }

        // PV: each V frag feeds both substrips (2 MFMAs per LDS read)
        const int prb0 = (w * 32 + lane16) * 64;
        const int prb1 = (w * 32 + 16 + lane16) * 64;
        __builtin_amdgcn_s_setprio(1);
#pragma unroll
        for (int kk = 0; kk < 2; ++kk) {
          const s16x8 pf0 = *(const s16x8*)&Psm[prb0 + ((kk * 32 + quad * 8) ^ swz)];
          const s16x8 pf1 = *(const s16x8*)&Psm[prb1 + ((kk * 32 + quad * 8) ^ swz)];
#pragma unroll
          for (int ntd = 0; ntd < 8; ++ntd) {
            const s16x8 vf =
                *(const s16x8*)&Vb[(ntd * 16 + lane16) * 64 + ((kk * 32 + quad * 8) ^ swz)];
            o[0][ntd] = __builtin_amdgcn_mfma_f32_16x16x32_bf16(pf0, vf, o[0][ntd], 0, 0, 0);
            o[1][ntd] = __builtin_amdgcn_mfma_f32_16x16x32_bf16(pf1, vf, o[1][ntd], 0, 0, 0);
          }
        }
        __builtin_amdgcn_s_setprio(0);
      }

      if (tl + 1 < ntl) WRITET(cur ^ 1);   // buf c^1's last readers passed the
      __syncthreads();                     // previous barrier
      cur ^= 1;
    }

    // normalize and store: O row q = s*16 + quad*4+r, col d = ntd*16+lane16
#pragma unroll
    for (int s = 0; s < 2; ++s)
#pragma unroll
      for (int r = 0; r < 4; ++r) {
        const float lr = __shfl(l_i[s], quad * 4 + r);
        const float inv = 1.f / lr;
        const size_t base =
            ((size_t)(b * 2048 + qw0 + s * 16 + quad * 4 + r)) * 2048 +
            h * 128 + lane16;
#pragma unroll
        for (int ntd = 0; ntd < 8; ++ntd)
          og[base + ntd * 16] = f2bf(o[s][ntd][r] * inv);
      }
  }
#undef LOADT
#undef WRITET
}

// ---------------------------------------------------------------------------
extern "C" void kernel_launch(void* const* d_in, const int* in_sizes, int n_in,
                              void* d_out, int out_size, void* d_ws,
                              size_t ws_size, hipStream_t stream)
{
  const float* x  = (const float*)d_in[0];
  const float* wq = (const float*)d_in[1];
  const float* bq = (const float*)d_in[2];
  const float* wk = (const float*)d_in[3];
  const float* bk = (const float*)d_in[4];
  const float* wv = (const float*)d_in[5];
  const float* bv = (const float*)d_in[6];
  const float* wo = (const float*)d_in[7];
  const float* bo = (const float*)d_in[8];
  float* out = (float*)d_out;

  // ws layout (77 MiB used; ws_size >= 80 MiB):
  //   xb  @0      32 MiB  [8192][2048] bf16; dead after KV-proj -> wob reuses @0
  //   wqb @32MiB   8 MiB; wkb @40MiB 2 MiB; wvb @42MiB 2 MiB (wkb||wvb = [1024][2048])
  //   qws @44MiB  32 MiB  [8192][2048] bf16; attention output in place
  //   tab @76MiB   1 MiB  float2[2048][64] rope cos/sin
  // d_out doubles as scratch: kws @out+0 8 MiB; vtw @out+8M 8 MiB; vtmp @out+16M 8 MiB
  char* ws = (char*)d_ws;
  short* xb  = (short*)ws;
  short* wqb = (short*)(ws + (32ull << 20));
  short* wkb = (short*)(ws + (40ull << 20));
  short* wvb = (short*)(ws + (42ull << 20));
  short* qws = (short*)(ws + (44ull << 20));
  float2* tab = (float2*)(ws + (76ull << 20));
  short* wob = xb;
  short* kws = (short*)d_out;
  short* vtw = (short*)((char*)d_out + (8ull << 20));
  short* vtmp = (short*)((char*)d_out + (16ull << 20));

  const dim3 blk(256);
  cvt_kernel<<<16384, blk, 0, stream>>>(x, xb);
  wcvt_kernel<<<6656, blk, 0, stream>>>(wq, wk, wv, wqb, wkb, wvb, tab);
  // projections: Q on 256^2 8-phase; K+V merged (wkb||wvb contiguous), V row-major
  gemm256_bt<<<dim3(8, 32), dim3(512), 0, stream>>>(xb, wqb, bq, qws, 8192, 2048, 2048, 0);
  gemm_bt<<<dim3(8, 64), blk, 0, stream>>>(xb, wkb, bk, bv, kws, vtmp, 8192, 1024, 2048, 3);
  trans_kernel<<<dim3(128, 8), blk, 0, stream>>>(vtmp, vtw);
  rope_kernel<<<8192, blk, 0, stream>>>(kws, 2, tab);   // K only; Q-rope fused in attn
  cvt_kernel<<<4096, blk, 0, stream>>>(wo, wob);        // after KV-proj (xb dead)
  attn_kernel<<<dim3(8, 16, 4), blk, 0, stream>>>(qws, kws, vtw, qws, tab);
  gemm256_bt<<<dim3(8, 32), dim3(512), 0, stream>>>(qws, wob, bo, out, 8192, 2048, 2048, 1);
}

// Round 9
// 518.331 us; speedup vs baseline: 1.1563x; 1.1563x over previous
//
#include <hip/hip_runtime.h>
#include <stdint.h>
#include <math.h>

typedef __attribute__((ext_vector_type(8))) short s16x8;
typedef __attribute__((ext_vector_type(4))) short s16x4;
typedef __attribute__((ext_vector_type(4))) float f32x4;

#define NEGH (-1.0e30f)

__device__ __forceinline__ short f2bf(float f) {
  union { float f; unsigned int i; } c; c.f = f;
  unsigned int lsb = (c.i >> 16) & 1u;
  c.i += 0x7fffu + lsb;
  return (short)(c.i >> 16);
}
__device__ __forceinline__ float bf2f(short u) {
  union { unsigned int i; float f; } c;
  c.i = ((unsigned int)(unsigned short)u) << 16;
  return c.f;
}

// async global->LDS, 16B per lane. LDS dest must be wave-uniform base + lane*16.
#define GLOAD_LDS16(gp, lp)                                                  \
  __builtin_amdgcn_global_load_lds(                                          \
      (__attribute__((address_space(1))) void*)(void*)(gp),                  \
      (__attribute__((address_space(3))) void*)(lp), 16, 0, 0)

// ---------------------------------------------------------------------------
// fp32 -> bf16 conversion, 4 elements/thread. n must be divisible by 1024.
// ---------------------------------------------------------------------------
__global__ __launch_bounds__(256) void cvt_kernel(const float* __restrict__ in,
                                                  short* __restrict__ out)
{
  const size_t i = ((size_t)blockIdx.x * 256 + threadIdx.x) * 4;
  const float4 v = *(const float4*)(in + i);
  s16x4 o = { f2bf(v.x), f2bf(v.y), f2bf(v.z), f2bf(v.w) };
  *(s16x4*)(out + i) = o;
}

// ---------------------------------------------------------------------------
// Merged weight conversions + rope table (saves 3 launches):
// blocks [0,4096) wq; [4096,5120) wk; [5120,6144) wv; [6144,6656) rope tab.
// ---------------------------------------------------------------------------
__global__ __launch_bounds__(256) void wcvt_kernel(
    const float* __restrict__ wq, const float* __restrict__ wk,
    const float* __restrict__ wv, short* __restrict__ wqb,
    short* __restrict__ wkb, short* __restrict__ wvb,
    float2* __restrict__ tab)
{
  const int bid = blockIdx.x;
  if (bid < 6144) {
    const float* in; short* out; int lb;
    if (bid < 4096)      { in = wq; out = wqb; lb = bid; }
    else if (bid < 5120) { in = wk; out = wkb; lb = bid - 4096; }
    else                 { in = wv; out = wvb; lb = bid - 5120; }
    const size_t i = ((size_t)lb * 256 + threadIdx.x) * 4;
    const float4 v = *(const float4*)(in + i);
    s16x4 o = { f2bf(v.x), f2bf(v.y), f2bf(v.z), f2bf(v.w) };
    *(s16x4*)(out + i) = o;
  } else {
    const int i = (bid - 6144) * 256 + threadIdx.x;   // 131072
    const int d = i & 63;
    const float fr = (float)(i >> 6) * exp2f((float)d * -0.20762050593048584f);
    float sn, cs;
    sincosf(fr, &sn, &cs);
    tab[i] = make_float2(cs, sn);
  }
}

// ---------------------------------------------------------------------------
// GEMM (small-N): C[M,N] = A[M,K] * W[N,K]^T + bias[N]. 128x128 tile, BK=64,
// 256 threads. omode: 0 = bf16 C row-major; 1 = fp32 C row-major;
// 3 = split KV: n<512 -> bf16 C[m*512+n] (bias), n>=512 -> bf16 C2[m*512+n-512]
//     (bias2). XCD remap for grid 8x64 (KV call).
// ---------------------------------------------------------------------------
__global__ __launch_bounds__(256) void gemm_bt(
    const short* __restrict__ A, const short* __restrict__ W,
    const float* __restrict__ bias, const float* __restrict__ bias2,
    void* __restrict__ C, void* __restrict__ C2,
    int M, int N, int K, int omode)
{
  __shared__ __align__(16) short As[128 * 64];
  __shared__ __align__(16) short Bs[128 * 64];

  const int t = threadIdx.x;
  const int l = t & 63;
  const int w = t >> 6;
  const int lane16 = l & 15;
  const int quad = l >> 4;
  const int wm = w >> 1, wn = w & 1;

  int bx = blockIdx.x, by = blockIdx.y;
  if (gridDim.x == 8 && gridDim.y == 64) {       // KV call: XCD-aware remap
    const int lid = blockIdx.x + 8 * blockIdx.y; // 0..511, x fastest
    const int xcd = lid & 7, idx = lid >> 3;     // idx 0..63
    by = xcd * 8 + (idx >> 3);                   // 0..63
    bx = idx & 7;                                // 0..7
  }
  const int mb0 = by * 128;
  const int nb0 = bx * 128;

  const f32x4 zero = {0.f, 0.f, 0.f, 0.f};
  f32x4 acc[4][4];
#pragma unroll
  for (int i = 0; i < 4; ++i)
#pragma unroll
    for (int j = 0; j < 4; ++j) acc[i][j] = zero;

  const int sr = t >> 3;
  const int sp = t & 7;
  const short* Ag = A + (size_t)(mb0 + sr) * K + sp * 8;
  const short* Wg = W + (size_t)(nb0 + sr) * K + sp * 8;
  short* Al = As + t * 8;
  short* Bl = Bs + t * 8;

  const int nkt = K >> 6;
  for (int kt = 0; kt < nkt; ++kt) {
    __syncthreads();
    const int kof = kt * 64;
#pragma unroll
    for (int it = 0; it < 4; ++it) {
      GLOAD_LDS16(Ag + kof + (size_t)(it * 32) * K, Al + it * 2048);
      GLOAD_LDS16(Wg + kof + (size_t)(it * 32) * K, Bl + it * 2048);
    }
    __syncthreads();
#pragma unroll
    for (int kk = 0; kk < 2; ++kk) {
      s16x8 af[4], bf[4];
#pragma unroll
      for (int mi = 0; mi < 4; ++mi)
        af[mi] = *(const s16x8*)&As[(wm * 64 + mi * 16 + lane16) * 64 +
                                    kk * 32 + quad * 8];
#pragma unroll
      for (int ni = 0; ni < 4; ++ni)
        bf[ni] = *(const s16x8*)&Bs[(wn * 64 + ni * 16 + lane16) * 64 +
                                    kk * 32 + quad * 8];
#pragma unroll
      for (int mi = 0; mi < 4; ++mi)
#pragma unroll
        for (int ni = 0; ni < 4; ++ni)
          acc[mi][ni] = __builtin_amdgcn_mfma_f32_16x16x32_bf16(
              af[mi], bf[ni], acc[mi][ni], 0, 0, 0);
    }
  }

#pragma unroll
  for (int ni = 0; ni < 4; ++ni) {
    const int n = nb0 + wn * 64 + ni * 16 + lane16;
    const float bvx = (omode == 3 && n >= 512) ? bias2[n - 512] : bias[n];
#pragma unroll
    for (int mi = 0; mi < 4; ++mi) {
      const int m0 = mb0 + wm * 64 + mi * 16 + quad * 4;
#pragma unroll
      for (int r = 0; r < 4; ++r) {
        const int m = m0 + r;
        const float v = acc[mi][ni][r] + bvx;
        if (omode == 0) {
          ((short*)C)[(size_t)m * N + n] = f2bf(v);
        } else if (omode == 1) {
          ((float*)C)[(size_t)m * N + n] = v;
        } else {
          if (n < 512) ((short*)C)[(size_t)m * 512 + n] = f2bf(v);
          else         ((short*)C2)[(size_t)m * 512 + (n - 512)] = f2bf(v);
        }
      }
    }
  }
}

// ---------------------------------------------------------------------------
// GEMM (big): 256x256 tile, BK=64, 512 threads = 8 waves (2M x 4N), 8-phase
// schedule (T2+T3+T4+T5), counted vmcnt(6) at P4/P8 only (r7 ledger).
// XCD remap for grid 8x32. omode: 0 = bf16 C; 1 = fp32 C.
// ---------------------------------------------------------------------------
__global__ __launch_bounds__(512, 2) void gemm256_bt(
    const short* __restrict__ A, const short* __restrict__ W,
    const float* __restrict__ bias, void* __restrict__ C,
    int M, int N, int K, int omode)
{
  __shared__ __align__(16) short Asm[2 * 16384];   // [buf][kk][row][32]
  __shared__ __align__(16) short Bsm[2 * 16384];

  const int t = threadIdx.x;
  const int l = t & 63;
  const int w = t >> 6;                // 0..7
  const int lane16 = l & 15;
  const int quad = l >> 4;
  const int wm = w >> 2;               // 0..1
  const int wn = w & 3;                // 0..3

  int bx = blockIdx.x, by = blockIdx.y;
  if (gridDim.x == 8 && gridDim.y == 32) {
    const int bid = blockIdx.y * 8 + blockIdx.x;   // 0..255, x fastest
    const int xcd = bid & 7, idx = bid >> 3;       // idx 0..31
    const int xc = xcd & 3, yc = xcd >> 2;         // 4 x-chunks x 2 y-chunks
    bx = xc * 2 + (idx & 1);                       // 0..7
    by = yc * 16 + (idx >> 1);                     // 0..31
  }
  const int mb0 = by * 256;
  const int nb0 = bx * 256;

  const f32x4 zero = {0.f, 0.f, 0.f, 0.f};
  f32x4 acc[8][4];
#pragma unroll
  for (int i = 0; i < 8; ++i)
#pragma unroll
    for (int j = 0; j < 4; ++j) acc[i][j] = zero;

  const int srow = t >> 2;                       // 0..127
  const int scs = (t & 3) ^ ((t >> 3) & 3);      // pre-swizzled source chunk
  const short* Ag = A + (size_t)(mb0 + srow) * K + scs * 8;
  const short* Wg = W + (size_t)(nb0 + srow) * K + scs * 8;
  const size_t rstep = (size_t)128 * K;

#define STAGE_A(b, kt, kh)                                                    \
  do {                                                                        \
    const size_t ko_ = (size_t)(kt) * 64 + (kh) * 32;                         \
    GLOAD_LDS16(Ag + ko_,         Asm + (b) * 16384 + (kh) * 8192 + t * 8);   \
    GLOAD_LDS16(Ag + ko_ + rstep, Asm + (b) * 16384 + (kh) * 8192 + 4096 + t * 8); \
  } while (0)
#define STAGE_B(b, kt, kh)                                                    \
  do {                                                                        \
    const size_t ko_ = (size_t)(kt) * 64 + (kh) * 32;                         \
    GLOAD_LDS16(Wg + ko_,         Bsm + (b) * 16384 + (kh) * 8192 + t * 8);   \
    GLOAD_LDS16(Wg + ko_ + rstep, Bsm + (b) * 16384 + (kh) * 8192 + 4096 + t * 8); \
  } while (0)

#define VMW6                                                                  \
  asm volatile("s_waitcnt vmcnt(6)" ::: "memory");                            \
  __builtin_amdgcn_sched_barrier(0);

  s16x8 bfr[4];

#define DO_PHASE(BUF, KK, MG, READB, STAGE_STMT, VM_STMT)                     \
  {                                                                           \
    const short* Abase = Asm + (BUF) * 16384 + (KK) * 8192;                   \
    const short* Bbase = Bsm + (BUF) * 16384 + (KK) * 8192;                   \
    if (READB) {                                                              \
      _Pragma("unroll")                                                       \
      for (int ni = 0; ni < 4; ++ni) {                                        \
        const int nr = wn * 64 + ni * 16 + lane16;                            \
        bfr[ni] = *(const s16x8*)(Bbase + nr * 32 +                           \
                                  ((quad ^ ((nr >> 1) & 3)) << 3));           \
      }                                                                       \
    }                                                                         \
    s16x8 afr[4];                                                             \
    _Pragma("unroll")                                                         \
    for (int mi2 = 0; mi2 < 4; ++mi2) {                                       \
      const int mr = wm * 128 + (MG) * 64 + mi2 * 16 + lane16;                \
      afr[mi2] = *(const s16x8*)(Abase + mr * 32 +                            \
                                 ((quad ^ ((mr >> 1) & 3)) << 3));            \
    }                                                                         \
    STAGE_STMT;                                                               \
    __builtin_amdgcn_s_barrier();                                             \
    asm volatile("s_waitcnt lgkmcnt(0)" ::: "memory");                        \
    __builtin_amdgcn_sched_barrier(0);                                        \
    __builtin_amdgcn_s_setprio(1);                                            \
    _Pragma("unroll")                                                         \
    for (int mi2 = 0; mi2 < 4; ++mi2)                                         \
      _Pragma("unroll")                                                       \
      for (int ni = 0; ni < 4; ++ni)                                          \
        acc[(MG) * 4 + mi2][ni] = __builtin_amdgcn_mfma_f32_16x16x32_bf16(    \
            afr[mi2], bfr[ni], acc[(MG) * 4 + mi2][ni], 0, 0, 0);             \
    __builtin_amdgcn_s_setprio(0);                                            \
    VM_STMT                                                                   \
    __builtin_amdgcn_s_barrier();                                             \
  }

  const int NT = K >> 6;               // K-tiles (even; >= 2)

  // prologue: 7 stages (14 loads); wait until buf0 (loads 1-8) landed.
  STAGE_B(0, 0, 0); STAGE_A(0, 0, 0); STAGE_B(0, 0, 1); STAGE_A(0, 0, 1);
  STAGE_B(1, 1, 0); STAGE_A(1, 1, 0); STAGE_B(1, 1, 1);
  asm volatile("s_waitcnt vmcnt(6)" ::: "memory");
  __builtin_amdgcn_sched_barrier(0);
  __builtin_amdgcn_s_barrier();

  for (int i2 = 0; i2 < NT; i2 += 2) {
    const int tp1 = (i2 + 1 < NT) ? i2 + 1 : NT - 1;
    const int tp2 = (i2 + 2 < NT) ? i2 + 2 : NT - 1;
    const int tp3 = (i2 + 3 < NT) ? i2 + 3 : NT - 1;
    DO_PHASE(0, 0, 0, true,  STAGE_A(1, tp1, 1), )        // P1
    DO_PHASE(0, 0, 1, false, STAGE_B(0, tp2, 0), )        // P2
    DO_PHASE(0, 1, 0, true,  STAGE_A(0, tp2, 0), )        // P3
    DO_PHASE(0, 1, 1, false, STAGE_B(0, tp2, 1), VMW6)    // P4
    DO_PHASE(1, 0, 0, true,  STAGE_A(0, tp2, 1), )        // P5
    DO_PHASE(1, 0, 1, false, STAGE_B(1, tp3, 0), )        // P6
    DO_PHASE(1, 1, 0, true,  STAGE_A(1, tp3, 0), )        // P7
    DO_PHASE(1, 1, 1, false, STAGE_B(1, tp3, 1), VMW6)    // P8
  }

#pragma unroll
  for (int ni = 0; ni < 4; ++ni) {
    const int n = nb0 + wn * 64 + ni * 16 + lane16;
    const float bv = bias[n];
#pragma unroll
    for (int mi = 0; mi < 8; ++mi) {
      const int m0 = mb0 + wm * 128 + mi * 16 + quad * 4;
#pragma unroll
      for (int r = 0; r < 4; ++r) {
        const float v = acc[mi][ni][r] + bv;
        if (omode == 0) ((short*)C)[(size_t)(m0 + r) * N + n] = f2bf(v);
        else            ((float*)C)[(size_t)(m0 + r) * N + n] = v;
      }
    }
  }
#undef DO_PHASE
#undef STAGE_A
#undef STAGE_B
#undef VMW6
}

// ---------------------------------------------------------------------------
// RoPE in place on bf16 buf[row][head*128 + d], pairs (d, d+64), pos = row%2048.
// (K only; Q-rope is fused into attn.)
// ---------------------------------------------------------------------------
__global__ __launch_bounds__(256) void rope_kernel(short* __restrict__ buf,
                                                   int lognh,
                                                   const float2* __restrict__ tab)
{
  const int idx = blockIdx.x * 256 + threadIdx.x;
  const int d = idx & 63;
  const int rest = idx >> 6;            // row*nh + h
  const int row = rest >> lognh;
  const int pos = row & 2047;
  const float2 cssn = tab[(pos << 6) | d];
  const float cs = cssn.x, sn = cssn.y;
  const size_t base = (size_t)rest * 128 + d;
  const float lo = bf2f(buf[base]);
  const float hi = bf2f(buf[base + 64]);
  buf[base]      = f2bf(lo * cs - hi * sn);
  buf[base + 64] = f2bf(hi * cs + lo * sn);
}

// ---------------------------------------------------------------------------
// Transpose V: in[m=b*2048+s][n(512)] -> out[(b*512+n)*2048 + s]. 64x64 LDS
// tiles, coalesced 16B on both sides. grid (128, 8), 256 threads.
// ---------------------------------------------------------------------------
__global__ __launch_bounds__(256) void trans_kernel(const short* __restrict__ in,
                                                    short* __restrict__ out)
{
  __shared__ short T[64 * 72];
  const int t = threadIdx.x;
  const int ms = blockIdx.x * 64;   // global m (= b*2048 + s) tile base
  const int ns = blockIdx.y * 64;   // n tile base
  const int b = ms >> 11;
  const int sl = ms & 2047;
  const int r = t >> 3, sg = t & 7;
#pragma unroll
  for (int j = 0; j < 2; ++j) {
    const uint4 v = *(const uint4*)(in + (size_t)(ms + r + 32 * j) * 512 + ns + sg * 8);
    *(uint4*)&T[(r + 32 * j) * 72 + sg * 8] = v;
  }
  __syncthreads();
#pragma unroll
  for (int j = 0; j < 2; ++j) {
    const int nr = r + 32 * j;
    s16x8 v;
#pragma unroll
    for (int i = 0; i < 8; ++i) v[i] = T[(sg * 8 + i) * 72 + nr];
    *(s16x8*)(out + ((size_t)(b * 512 + ns + nr)) * 2048 + sl + sg * 8) = v;
  }
}

// ---------------------------------------------------------------------------
// Flash attention, causal, GQA. r9: keep r8's 4-wave x 32-q-row structure
// (each K/V LDS fragment read feeds 2 MFMAs -> half the LDS amplification)
// but stage K/V via global_load_lds with PRE-SWIZZLED per-lane GLOBAL source
// (m173 pattern: linear LDS dest base+t*16, source seg XOR'd by row&7).
// This removes the 8x uint4 staging registers + all ds_writes that spilled
// r8 to scratch (WRITE_SIZE 403MB). Stored: LDS[row][s] = G[row][s^(row&7)];
// read uses col ^ ((row&7)<<3) with row&7 == lane16&7 -- same involution both
// sides. __syncthreads() drains the vmcnt at tile end (loads had the whole
// tile's compute to fly). Double-buffered, one barrier/tile, fused Q-RoPE,
// XCD remap. In-place og==qg safe.
// ---------------------------------------------------------------------------
__global__ __launch_bounds__(256, 2) void attn_kernel(
    const short* __restrict__ qg, const short* __restrict__ kg,
    const short* __restrict__ vtg, short* __restrict__ og,
    const float2* __restrict__ tab)
{
  __shared__ __align__(16) short Ksm[2 * 64 * 128];   // [buf][key][d], swizzled
  __shared__ __align__(16) short Vsm[2 * 128 * 64];   // [buf][d][key], swizzled
  __shared__ __align__(16) short Psm[128 * 64];       // [q][key], wave-private rows

  const int t = threadIdx.x;
  const int l = t & 63;
  const int w = t >> 6;                 // 0..3
  const int lane16 = l & 15;
  const int quad = l >> 4;

  // XCD remap: lid 0..511; group g = (b,kv) 0..15; two groups per XCD.
  const int lid = blockIdx.x + 8 * (blockIdx.y + 16 * blockIdx.z);
  const int xcd = lid & 7, idx = lid >> 3;        // idx 0..63
  const int g = xcd * 2 + (idx >> 5);             // 0..15
  const int wv_ = idx & 31;
  const int b = g >> 2, kv = g & 3;
  const int h = kv * 4 + (wv_ >> 3);
  const int jb = wv_ & 7;

  // DMA staging geometry (256 threads, 4 issues each of K and V, 16B/lane):
  // K: issue j covers rows j*16 + (t>>4); source seg = (t&15) ^ ((t>>4)&7)
  //    (row&7 == (t>>4)&7 since j*16 % 8 == 0). LDS dest linear: j*2048+t*8.
  // V: issue j covers rows j*32 + (t>>3); source seg = (t&7) ^ ((t>>3)&7).
  const int krow0 = t >> 4, kseg = (t & 15) ^ (krow0 & 7);
  const int vrow0 = t >> 3, vseg = (t & 7) ^ (vrow0 & 7);

  const short* kbaseptr = kg + ((size_t)(b * 2048)) * 512 + kv * 128;
  const short* vbaseptr = vtg + ((size_t)(b * 512 + kv * 128)) * 2048;

  const float SC = 0.08838834764831845f * 1.4426950408889634f; // rsqrt(128)*log2e
  const f32x4 zero = {0.f, 0.f, 0.f, 0.f};
  const int swz = (lane16 & 7) << 3;

#define STAGET(c)                                                             \
  do {                                                                        \
    GLOAD_LDS16(ksrc,          Ksm + (c) * 8192 + t * 8);                     \
    GLOAD_LDS16(ksrc + 8192,   Ksm + (c) * 8192 + 2048 + t * 8);              \
    GLOAD_LDS16(ksrc + 16384,  Ksm + (c) * 8192 + 4096 + t * 8);              \
    GLOAD_LDS16(ksrc + 24576,  Ksm + (c) * 8192 + 6144 + t * 8);              \
    GLOAD_LDS16(vsrc,          Vsm + (c) * 8192 + t * 8);                     \
    GLOAD_LDS16(vsrc + 65536,  Vsm + (c) * 8192 + 2048 + t * 8);              \
    GLOAD_LDS16(vsrc + 131072, Vsm + (c) * 8192 + 4096 + t * 8);              \
    GLOAD_LDS16(vsrc + 196608, Vsm + (c) * 8192 + 6144 + t * 8);              \
    ksrc += 64 * 512;                                                         \
    vsrc += 64;                                                               \
  } while (0)

  for (int sp2 = 0; sp2 < 2; ++sp2) {
    const int jj = sp2 ? (15 - jb) : jb;
    const int qb0 = jj * 128;
    const int qw0 = qb0 + w * 32;       // wave owns 32 q rows
    const int qmaxw = qw0 + 31;
    const int ntl = 2 * jj + 2;

    // per-strip staging pointers (advance per staged tile)
    const short* ksrc = kbaseptr + (size_t)krow0 * 512 + kseg * 8;
    const short* vsrc = vbaseptr + (size_t)vrow0 * 2048 + vseg * 8;

    // Q fragments with FUSED RoPE, per substrip s: rows qw0 + s*16 + lane16.
    s16x8 qf[2][4];
#pragma unroll
    for (int s = 0; s < 2; ++s) {
      const short* qrow =
          qg + ((size_t)(b * 2048 + qw0 + s * 16 + lane16)) * 2048 + h * 128 + quad * 8;
      s16x8 qr[4];
#pragma unroll
      for (int kk = 0; kk < 4; ++kk) qr[kk] = *(const s16x8*)(qrow + kk * 32);
      const float2* tb = tab + (((size_t)(qw0 + s * 16 + lane16)) << 6) + quad * 8;
#pragma unroll
      for (int kk = 0; kk < 2; ++kk) {
        float lo[8], hi[8];
#pragma unroll
        for (int j = 0; j < 8; ++j) {
          const float2 cs2 = tb[kk * 32 + j];
          const float l0 = bf2f(qr[kk][j]);
          const float h0 = bf2f(qr[kk + 2][j]);
          lo[j] = l0 * cs2.x - h0 * cs2.y;
          hi[j] = h0 * cs2.x + l0 * cs2.y;
        }
        union { unsigned int u[4]; s16x8 v; } plo, phi;
#pragma unroll
        for (int j = 0; j < 4; ++j) {
          asm("v_cvt_pk_bf16_f32 %0, %1, %2"
              : "=v"(plo.u[j]) : "v"(lo[2 * j]), "v"(lo[2 * j + 1]));
          asm("v_cvt_pk_bf16_f32 %0, %1, %2"
              : "=v"(phi.u[j]) : "v"(hi[2 * j]), "v"(hi[2 * j + 1]));
        }
        qf[s][kk] = plo.v;
        qf[s][kk + 2] = phi.v;
      }
    }

    f32x4 o[2][8];
#pragma unroll
    for (int s = 0; s < 2; ++s)
#pragma unroll
      for (int i = 0; i < 8; ++i) o[s][i] = zero;
    float m_i[2] = {NEGH, NEGH};
    float l_i[2] = {0.f, 0.f};

    // prologue: DMA tile 0 into buf 0
    STAGET(0);
    __syncthreads();                    // drains vmcnt
    int cur = 0;

    for (int tl = 0; tl < ntl; ++tl) {
      const int kbase = tl * 64;
      if (tl + 1 < ntl) STAGET(cur ^ 1);  // async DMA; flies under compute

      if (kbase <= qmaxw) {
        const short* Kb = Ksm + cur * 8192;
        const short* Vb = Vsm + cur * 8192;
        f32x4 st[2][4];
#pragma unroll
        for (int s = 0; s < 2; ++s)
#pragma unroll
          for (int mt = 0; mt < 4; ++mt) st[s][mt] = zero;
        // QK: each K a-frag feeds both substrips (2 MFMAs per LDS read)
        __builtin_amdgcn_s_setprio(1);
#pragma unroll
        for (int mt = 0; mt < 4; ++mt) {
          const int rb = (mt * 16 + lane16) * 128;
#pragma unroll
          for (int kk = 0; kk < 4; ++kk) {
            const s16x8 a = *(const s16x8*)&Kb[rb + ((kk * 32 + quad * 8) ^ swz)];
            st[0][mt] = __builtin_amdgcn_mfma_f32_16x16x32_bf16(a, qf[0][kk], st[0][mt], 0, 0, 0);
            st[1][mt] = __builtin_amdgcn_mfma_f32_16x16x32_bf16(a, qf[1][kk], st[1][mt], 0, 0, 0);
          }
        }
        __builtin_amdgcn_s_setprio(0);

        // ---- softmax on raw st per substrip ----
        const bool maskt = (kbase + 63 > qw0);
#pragma unroll
        for (int s = 0; s < 2; ++s) {
          const int qabs = qw0 + s * 16 + lane16;
          if (maskt) {
#pragma unroll
            for (int mt = 0; mt < 4; ++mt)
#pragma unroll
              for (int r = 0; r < 4; ++r) {
                if ((kbase + mt * 16 + quad * 4 + r) > qabs) st[s][mt][r] = NEGH;
              }
          }
          float tm[4];
#pragma unroll
          for (int mt = 0; mt < 4; ++mt)
            tm[mt] = fmaxf(fmaxf(st[s][mt][0], st[s][mt][1]),
                           fmaxf(st[s][mt][2], st[s][mt][3]));
          float tl_ = fmaxf(fmaxf(tm[0], tm[1]), fmaxf(tm[2], tm[3]));
          tl_ = fmaxf(tl_, __shfl_xor(tl_, 16));
          tl_ = fmaxf(tl_, __shfl_xor(tl_, 32));
          const float mnew = fmaxf(m_i[s], tl_);
          if (!__all(tl_ <= m_i[s])) {
            const float alpha = exp2f((m_i[s] - mnew) * SC);
            l_i[s] *= alpha;
#pragma unroll
            for (int r = 0; r < 4; ++r) {
              const float ar = __shfl(alpha, quad * 4 + r);
#pragma unroll
              for (int ntd = 0; ntd < 8; ++ntd) o[s][ntd][r] *= ar;
            }
          }
          m_i[s] = mnew;
          const float mS = mnew * SC;
          float rs = 0.f;
#pragma unroll
          for (int mt = 0; mt < 4; ++mt) {
            const float p0 = exp2f(fmaf(st[s][mt][0], SC, -mS));
            const float p1 = exp2f(fmaf(st[s][mt][1], SC, -mS));
            const float p2 = exp2f(fmaf(st[s][mt][2], SC, -mS));
            const float p3 = exp2f(fmaf(st[s][mt][3], SC, -mS));
            rs += (p0 + p1) + (p2 + p3);
            uint2 pk2;
            asm("v_cvt_pk_bf16_f32 %0, %1, %2" : "=v"(pk2.x) : "v"(p0), "v"(p1));
            asm("v_cvt_pk_bf16_f32 %0, %1, %2" : "=v"(pk2.y) : "v"(p2), "v"(p3));
            *(uint2*)&Psm[(w * 32 + s * 16 + lane16) * 64 +
                          ((mt * 16 + quad * 4) ^ swz)] = pk2;
          }
          rs += __shfl_xor(rs, 16);
          rs += __shfl_xor(rs, 32);
          l_i[s] += rs;
        }

        // PV: each V frag feeds both substrips (2 MFMAs per LDS read)
        const int prb0 = (w * 32 + lane16) * 64;
        const int prb1 = (w * 32 + 16 + lane16) * 64;
        __builtin_amdgcn_s_setprio(1);
#pragma unroll
        for (int kk = 0; kk < 2; ++kk) {
          const s16x8 pf0 = *(const s16x8*)&Psm[prb0 + ((kk * 32 + quad * 8) ^ swz)];
          const s16x8 pf1 = *(const s16x8*)&Psm[prb1 + ((kk * 32 + quad * 8) ^ swz)];
#pragma unroll
          for (int ntd = 0; ntd < 8; ++ntd) {
            const s16x8 vf =
                *(const s16x8*)&Vb[(ntd * 16 + lane16) * 64 + ((kk * 32 + quad * 8) ^ swz)];
            o[0][ntd] = __builtin_amdgcn_mfma_f32_16x16x32_bf16(pf0, vf, o[0][ntd], 0, 0, 0);
            o[1][ntd] = __builtin_amdgcn_mfma_f32_16x16x32_bf16(pf1, vf, o[1][ntd], 0, 0, 0);
          }
        }
        __builtin_amdgcn_s_setprio(0);
      }

      __syncthreads();                  // drains vmcnt: next buf's DMA landed;
      cur ^= 1;                         // buf cur's readers all passed
    }

    // normalize and store: O row q = s*16 + quad*4+r, col d = ntd*16+lane16
#pragma unroll
    for (int s = 0; s < 2; ++s)
#pragma unroll
      for (int r = 0; r < 4; ++r) {
        const float lr = __shfl(l_i[s], quad * 4 + r);
        const float inv = 1.f / lr;
        const size_t base =
            ((size_t)(b * 2048 + qw0 + s * 16 + quad * 4 + r)) * 2048 +
            h * 128 + lane16;
#pragma unroll
        for (int ntd = 0; ntd < 8; ++ntd)
          og[base + ntd * 16] = f2bf(o[s][ntd][r] * inv);
      }
  }
#undef STAGET
}

// ---------------------------------------------------------------------------
extern "C" void kernel_launch(void* const* d_in, const int* in_sizes, int n_in,
                              void* d_out, int out_size, void* d_ws,
                              size_t ws_size, hipStream_t stream)
{
  const float* x  = (const float*)d_in[0];
  const float* wq = (const float*)d_in[1];
  const float* bq = (const float*)d_in[2];
  const float* wk = (const float*)d_in[3];
  const float* bk = (const float*)d_in[4];
  const float* wv = (const float*)d_in[5];
  const float* bv = (const float*)d_in[6];
  const float* wo = (const float*)d_in[7];
  const float* bo = (const float*)d_in[8];
  float* out = (float*)d_out;

  // ws layout (77 MiB used; ws_size >= 80 MiB):
  //   xb  @0      32 MiB  [8192][2048] bf16; dead after KV-proj -> wob reuses @0
  //   wqb @32MiB   8 MiB; wkb @40MiB 2 MiB; wvb @42MiB 2 MiB (wkb||wvb = [1024][2048])
  //   qws @44MiB  32 MiB  [8192][2048] bf16; attention output in place
  //   tab @76MiB   1 MiB  float2[2048][64] rope cos/sin
  // d_out doubles as scratch: kws @out+0 8 MiB; vtw @out+8M 8 MiB; vtmp @out+16M 8 MiB
  char* ws = (char*)d_ws;
  short* xb  = (short*)ws;
  short* wqb = (short*)(ws + (32ull << 20));
  short* wkb = (short*)(ws + (40ull << 20));
  short* wvb = (short*)(ws + (42ull << 20));
  short* qws = (short*)(ws + (44ull << 20));
  float2* tab = (float2*)(ws + (76ull << 20));
  short* wob = xb;
  short* kws = (short*)d_out;
  short* vtw = (short*)((char*)d_out + (8ull << 20));
  short* vtmp = (short*)((char*)d_out + (16ull << 20));

  const dim3 blk(256);
  cvt_kernel<<<16384, blk, 0, stream>>>(x, xb);
  wcvt_kernel<<<6656, blk, 0, stream>>>(wq, wk, wv, wqb, wkb, wvb, tab);
  // projections: Q on 256^2 8-phase; K+V merged (wkb||wvb contiguous), V row-major
  gemm256_bt<<<dim3(8, 32), dim3(512), 0, stream>>>(xb, wqb, bq, qws, 8192, 2048, 2048, 0);
  gemm_bt<<<dim3(8, 64), blk, 0, stream>>>(xb, wkb, bk, bv, kws, vtmp, 8192, 1024, 2048, 3);
  trans_kernel<<<dim3(128, 8), blk, 0, stream>>>(vtmp, vtw);
  rope_kernel<<<8192, blk, 0, stream>>>(kws, 2, tab);   // K only; Q-rope fused in attn
  cvt_kernel<<<4096, blk, 0, stream>>>(wo, wob);        // after KV-proj (xb dead)
  attn_kernel<<<dim3(8, 16, 4), blk, 0, stream>>>(qws, kws, vtw, qws, tab);
  gemm256_bt<<<dim3(8, 32), dim3(512), 0, stream>>>(qws, wob, bo, out, 8192, 2048, 2048, 1);
}

// Round 10
// 495.081 us; speedup vs baseline: 1.2106x; 1.0470x over previous
//
#include <hip/hip_runtime.h>
#include <stdint.h>
#include <math.h>

typedef __attribute__((ext_vector_type(8))) short s16x8;
typedef __attribute__((ext_vector_type(4))) short s16x4;
typedef __attribute__((ext_vector_type(4))) float f32x4;
typedef __attribute__((ext_vector_type(16))) float f32x16;

#define NEGH (-1.0e30f)

__device__ __forceinline__ short f2bf(float f) {
  union { float f; unsigned int i; } c; c.f = f;
  unsigned int lsb = (c.i >> 16) & 1u;
  c.i += 0x7fffu + lsb;
  return (short)(c.i >> 16);
}
__device__ __forceinline__ float bf2f(short u) {
  union { unsigned int i; float f; } c;
  c.i = ((unsigned int)(unsigned short)u) << 16;
  return c.f;
}

// async global->LDS, 16B per lane. LDS dest must be wave-uniform base + lane*16.
#define GLOAD_LDS16(gp, lp)                                                  \
  __builtin_amdgcn_global_load_lds(                                          \
      (__attribute__((address_space(1))) void*)(void*)(gp),                  \
      (__attribute__((address_space(3))) void*)(lp), 16, 0, 0)

// ---------------------------------------------------------------------------
// fp32 -> bf16 conversion, 4 elements/thread. n must be divisible by 1024.
// ---------------------------------------------------------------------------
__global__ __launch_bounds__(256) void cvt_kernel(const float* __restrict__ in,
                                                  short* __restrict__ out)
{
  const size_t i = ((size_t)blockIdx.x * 256 + threadIdx.x) * 4;
  const float4 v = *(const float4*)(in + i);
  s16x4 o = { f2bf(v.x), f2bf(v.y), f2bf(v.z), f2bf(v.w) };
  *(s16x4*)(out + i) = o;
}

// ---------------------------------------------------------------------------
// Merged weight conversions + rope table:
// blocks [0,4096) wq; [4096,5120) wk; [5120,6144) wv; [6144,6656) rope tab.
// ---------------------------------------------------------------------------
__global__ __launch_bounds__(256) void wcvt_kernel(
    const float* __restrict__ wq, const float* __restrict__ wk,
    const float* __restrict__ wv, short* __restrict__ wqb,
    short* __restrict__ wkb, short* __restrict__ wvb,
    float2* __restrict__ tab)
{
  const int bid = blockIdx.x;
  if (bid < 6144) {
    const float* in; short* out; int lb;
    if (bid < 4096)      { in = wq; out = wqb; lb = bid; }
    else if (bid < 5120) { in = wk; out = wkb; lb = bid - 4096; }
    else                 { in = wv; out = wvb; lb = bid - 5120; }
    const size_t i = ((size_t)lb * 256 + threadIdx.x) * 4;
    const float4 v = *(const float4*)(in + i);
    s16x4 o = { f2bf(v.x), f2bf(v.y), f2bf(v.z), f2bf(v.w) };
    *(s16x4*)(out + i) = o;
  } else {
    const int i = (bid - 6144) * 256 + threadIdx.x;   // 131072
    const int d = i & 63;
    const float fr = (float)(i >> 6) * exp2f((float)d * -0.20762050593048584f);
    float sn, cs;
    sincosf(fr, &sn, &cs);
    tab[i] = make_float2(cs, sn);
  }
}

// ---------------------------------------------------------------------------
// GEMM (small-N): C[M,N] = A[M,K] * W[N,K]^T + bias[N]. 128x128 tile, BK=64,
// 256 threads. omode: 0 = bf16 C row-major; 1 = fp32 C row-major;
// 3 = split KV. XCD remap for grid 8x64 (KV call).
// ---------------------------------------------------------------------------
__global__ __launch_bounds__(256) void gemm_bt(
    const short* __restrict__ A, const short* __restrict__ W,
    const float* __restrict__ bias, const float* __restrict__ bias2,
    void* __restrict__ C, void* __restrict__ C2,
    int M, int N, int K, int omode)
{
  __shared__ __align__(16) short As[128 * 64];
  __shared__ __align__(16) short Bs[128 * 64];

  const int t = threadIdx.x;
  const int l = t & 63;
  const int w = t >> 6;
  const int lane16 = l & 15;
  const int quad = l >> 4;
  const int wm = w >> 1, wn = w & 1;

  int bx = blockIdx.x, by = blockIdx.y;
  if (gridDim.x == 8 && gridDim.y == 64) {       // KV call: XCD-aware remap
    const int lid = blockIdx.x + 8 * blockIdx.y;
    const int xcd = lid & 7, idx = lid >> 3;
    by = xcd * 8 + (idx >> 3);
    bx = idx & 7;
  }
  const int mb0 = by * 128;
  const int nb0 = bx * 128;

  const f32x4 zero = {0.f, 0.f, 0.f, 0.f};
  f32x4 acc[4][4];
#pragma unroll
  for (int i = 0; i < 4; ++i)
#pragma unroll
    for (int j = 0; j < 4; ++j) acc[i][j] = zero;

  const int sr = t >> 3;
  const int sp = t & 7;
  const short* Ag = A + (size_t)(mb0 + sr) * K + sp * 8;
  const short* Wg = W + (size_t)(nb0 + sr) * K + sp * 8;
  short* Al = As + t * 8;
  short* Bl = Bs + t * 8;

  const int nkt = K >> 6;
  for (int kt = 0; kt < nkt; ++kt) {
    __syncthreads();
    const int kof = kt * 64;
#pragma unroll
    for (int it = 0; it < 4; ++it) {
      GLOAD_LDS16(Ag + kof + (size_t)(it * 32) * K, Al + it * 2048);
      GLOAD_LDS16(Wg + kof + (size_t)(it * 32) * K, Bl + it * 2048);
    }
    __syncthreads();
#pragma unroll
    for (int kk = 0; kk < 2; ++kk) {
      s16x8 af[4], bf[4];
#pragma unroll
      for (int mi = 0; mi < 4; ++mi)
        af[mi] = *(const s16x8*)&As[(wm * 64 + mi * 16 + lane16) * 64 +
                                    kk * 32 + quad * 8];
#pragma unroll
      for (int ni = 0; ni < 4; ++ni)
        bf[ni] = *(const s16x8*)&Bs[(wn * 64 + ni * 16 + lane16) * 64 +
                                    kk * 32 + quad * 8];
#pragma unroll
      for (int mi = 0; mi < 4; ++mi)
#pragma unroll
        for (int ni = 0; ni < 4; ++ni)
          acc[mi][ni] = __builtin_amdgcn_mfma_f32_16x16x32_bf16(
              af[mi], bf[ni], acc[mi][ni], 0, 0, 0);
    }
  }

#pragma unroll
  for (int ni = 0; ni < 4; ++ni) {
    const int n = nb0 + wn * 64 + ni * 16 + lane16;
    const float bvx = (omode == 3 && n >= 512) ? bias2[n - 512] : bias[n];
#pragma unroll
    for (int mi = 0; mi < 4; ++mi) {
      const int m0 = mb0 + wm * 64 + mi * 16 + quad * 4;
#pragma unroll
      for (int r = 0; r < 4; ++r) {
        const int m = m0 + r;
        const float v = acc[mi][ni][r] + bvx;
        if (omode == 0) {
          ((short*)C)[(size_t)m * N + n] = f2bf(v);
        } else if (omode == 1) {
          ((float*)C)[(size_t)m * N + n] = v;
        } else {
          if (n < 512) ((short*)C)[(size_t)m * 512 + n] = f2bf(v);
          else         ((short*)C2)[(size_t)m * 512 + (n - 512)] = f2bf(v);
        }
      }
    }
  }
}

// ---------------------------------------------------------------------------
// GEMM (big): 256x256 tile, BK=64, 512 threads = 8 waves (2M x 4N), 8-phase
// schedule (T2+T3+T4+T5), counted vmcnt(6) at P4/P8 only (r7 ledger).
// XCD remap for grid 8x32. omode: 0 = bf16 C; 1 = fp32 C.
// ---------------------------------------------------------------------------
__global__ __launch_bounds__(512, 2) void gemm256_bt(
    const short* __restrict__ A, const short* __restrict__ W,
    const float* __restrict__ bias, void* __restrict__ C,
    int M, int N, int K, int omode)
{
  __shared__ __align__(16) short Asm[2 * 16384];   // [buf][kk][row][32]
  __shared__ __align__(16) short Bsm[2 * 16384];

  const int t = threadIdx.x;
  const int l = t & 63;
  const int w = t >> 6;
  const int lane16 = l & 15;
  const int quad = l >> 4;
  const int wm = w >> 2;
  const int wn = w & 3;

  int bx = blockIdx.x, by = blockIdx.y;
  if (gridDim.x == 8 && gridDim.y == 32) {
    const int bid = blockIdx.y * 8 + blockIdx.x;
    const int xcd = bid & 7, idx = bid >> 3;
    const int xc = xcd & 3, yc = xcd >> 2;
    bx = xc * 2 + (idx & 1);
    by = yc * 16 + (idx >> 1);
  }
  const int mb0 = by * 256;
  const int nb0 = bx * 256;

  const f32x4 zero = {0.f, 0.f, 0.f, 0.f};
  f32x4 acc[8][4];
#pragma unroll
  for (int i = 0; i < 8; ++i)
#pragma unroll
    for (int j = 0; j < 4; ++j) acc[i][j] = zero;

  const int srow = t >> 2;
  const int scs = (t & 3) ^ ((t >> 3) & 3);
  const short* Ag = A + (size_t)(mb0 + srow) * K + scs * 8;
  const short* Wg = W + (size_t)(nb0 + srow) * K + scs * 8;
  const size_t rstep = (size_t)128 * K;

#define STAGE_A(b, kt, kh)                                                    \
  do {                                                                        \
    const size_t ko_ = (size_t)(kt) * 64 + (kh) * 32;                         \
    GLOAD_LDS16(Ag + ko_,         Asm + (b) * 16384 + (kh) * 8192 + t * 8);   \
    GLOAD_LDS16(Ag + ko_ + rstep, Asm + (b) * 16384 + (kh) * 8192 + 4096 + t * 8); \
  } while (0)
#define STAGE_B(b, kt, kh)                                                    \
  do {                                                                        \
    const size_t ko_ = (size_t)(kt) * 64 + (kh) * 32;                         \
    GLOAD_LDS16(Wg + ko_,         Bsm + (b) * 16384 + (kh) * 8192 + t * 8);   \
    GLOAD_LDS16(Wg + ko_ + rstep, Bsm + (b) * 16384 + (kh) * 8192 + 4096 + t * 8); \
  } while (0)

#define VMW6                                                                  \
  asm volatile("s_waitcnt vmcnt(6)" ::: "memory");                            \
  __builtin_amdgcn_sched_barrier(0);

  s16x8 bfr[4];

#define DO_PHASE(BUF, KK, MG, READB, STAGE_STMT, VM_STMT)                     \
  {                                                                           \
    const short* Abase = Asm + (BUF) * 16384 + (KK) * 8192;                   \
    const short* Bbase = Bsm + (BUF) * 16384 + (KK) * 8192;                   \
    if (READB) {                                                              \
      _Pragma("unroll")                                                       \
      for (int ni = 0; ni < 4; ++ni) {                                        \
        const int nr = wn * 64 + ni * 16 + lane16;                            \
        bfr[ni] = *(const s16x8*)(Bbase + nr * 32 +                           \
                                  ((quad ^ ((nr >> 1) & 3)) << 3));           \
      }                                                                       \
    }                                                                         \
    s16x8 afr[4];                                                             \
    _Pragma("unroll")                                                         \
    for (int mi2 = 0; mi2 < 4; ++mi2) {                                       \
      const int mr = wm * 128 + (MG) * 64 + mi2 * 16 + lane16;                \
      afr[mi2] = *(const s16x8*)(Abase + mr * 32 +                            \
                                 ((quad ^ ((mr >> 1) & 3)) << 3));            \
    }                                                                         \
    STAGE_STMT;                                                               \
    __builtin_amdgcn_s_barrier();                                             \
    asm volatile("s_waitcnt lgkmcnt(0)" ::: "memory");                        \
    __builtin_amdgcn_sched_barrier(0);                                        \
    __builtin_amdgcn_s_setprio(1);                                            \
    _Pragma("unroll")                                                         \
    for (int mi2 = 0; mi2 < 4; ++mi2)                                         \
      _Pragma("unroll")                                                       \
      for (int ni = 0; ni < 4; ++ni)                                          \
        acc[(MG) * 4 + mi2][ni] = __builtin_amdgcn_mfma_f32_16x16x32_bf16(    \
            afr[mi2], bfr[ni], acc[(MG) * 4 + mi2][ni], 0, 0, 0);             \
    __builtin_amdgcn_s_setprio(0);                                            \
    VM_STMT                                                                   \
    __builtin_amdgcn_s_barrier();                                             \
  }

  const int NT = K >> 6;

  STAGE_B(0, 0, 0); STAGE_A(0, 0, 0); STAGE_B(0, 0, 1); STAGE_A(0, 0, 1);
  STAGE_B(1, 1, 0); STAGE_A(1, 1, 0); STAGE_B(1, 1, 1);
  asm volatile("s_waitcnt vmcnt(6)" ::: "memory");
  __builtin_amdgcn_sched_barrier(0);
  __builtin_amdgcn_s_barrier();

  for (int i2 = 0; i2 < NT; i2 += 2) {
    const int tp1 = (i2 + 1 < NT) ? i2 + 1 : NT - 1;
    const int tp2 = (i2 + 2 < NT) ? i2 + 2 : NT - 1;
    const int tp3 = (i2 + 3 < NT) ? i2 + 3 : NT - 1;
    DO_PHASE(0, 0, 0, true,  STAGE_A(1, tp1, 1), )        // P1
    DO_PHASE(0, 0, 1, false, STAGE_B(0, tp2, 0), )        // P2
    DO_PHASE(0, 1, 0, true,  STAGE_A(0, tp2, 0), )        // P3
    DO_PHASE(0, 1, 1, false, STAGE_B(0, tp2, 1), VMW6)    // P4
    DO_PHASE(1, 0, 0, true,  STAGE_A(0, tp2, 1), )        // P5
    DO_PHASE(1, 0, 1, false, STAGE_B(1, tp3, 0), )        // P6
    DO_PHASE(1, 1, 0, true,  STAGE_A(1, tp3, 0), )        // P7
    DO_PHASE(1, 1, 1, false, STAGE_B(1, tp3, 1), VMW6)    // P8
  }

#pragma unroll
  for (int ni = 0; ni < 4; ++ni) {
    const int n = nb0 + wn * 64 + ni * 16 + lane16;
    const float bv = bias[n];
#pragma unroll
    for (int mi = 0; mi < 8; ++mi) {
      const int m0 = mb0 + wm * 128 + mi * 16 + quad * 4;
#pragma unroll
      for (int r = 0; r < 4; ++r) {
        const float v = acc[mi][ni][r] + bv;
        if (omode == 0) ((short*)C)[(size_t)(m0 + r) * N + n] = f2bf(v);
        else            ((float*)C)[(size_t)(m0 + r) * N + n] = v;
      }
    }
  }
#undef DO_PHASE
#undef STAGE_A
#undef STAGE_B
#undef VMW6
}

// ---------------------------------------------------------------------------
// RoPE in place on bf16 buf[row][head*128 + d] (K only; Q fused in attn).
// ---------------------------------------------------------------------------
__global__ __launch_bounds__(256) void rope_kernel(short* __restrict__ buf,
                                                   int lognh,
                                                   const float2* __restrict__ tab)
{
  const int idx = blockIdx.x * 256 + threadIdx.x;
  const int d = idx & 63;
  const int rest = idx >> 6;
  const int row = rest >> lognh;
  const int pos = row & 2047;
  const float2 cssn = tab[(pos << 6) | d];
  const float cs = cssn.x, sn = cssn.y;
  const size_t base = (size_t)rest * 128 + d;
  const float lo = bf2f(buf[base]);
  const float hi = bf2f(buf[base + 64]);
  buf[base]      = f2bf(lo * cs - hi * sn);
  buf[base + 64] = f2bf(hi * cs + lo * sn);
}

// ---------------------------------------------------------------------------
// Transpose V: in[m=b*2048+s][n(512)] -> out[(b*512+n)*2048 + s].
// ---------------------------------------------------------------------------
__global__ __launch_bounds__(256) void trans_kernel(const short* __restrict__ in,
                                                    short* __restrict__ out)
{
  __shared__ short T[64 * 72];
  const int t = threadIdx.x;
  const int ms = blockIdx.x * 64;
  const int ns = blockIdx.y * 64;
  const int b = ms >> 11;
  const int sl = ms & 2047;
  const int r = t >> 3, sg = t & 7;
#pragma unroll
  for (int j = 0; j < 2; ++j) {
    const uint4 v = *(const uint4*)(in + (size_t)(ms + r + 32 * j) * 512 + ns + sg * 8);
    *(uint4*)&T[(r + 32 * j) * 72 + sg * 8] = v;
  }
  __syncthreads();
#pragma unroll
  for (int j = 0; j < 2; ++j) {
    const int nr = r + 32 * j;
    s16x8 v;
#pragma unroll
    for (int i = 0; i < 8; ++i) v[i] = T[(sg * 8 + i) * 72 + nr];
    *(s16x8*)(out + ((size_t)(b * 512 + ns + nr)) * 2048 + sl + sg * 8) = v;
  }
}

// ---------------------------------------------------------------------------
// Flash attention, causal, GQA. r10: m214-class 32x32 SWAPPED structure.
// 4 waves x 32 q-rows. Per 64-key tile: QK = mfma_32x32x16(A=K, B=Q^T) x 2
// key-blocks x 8 d-steps -> C col=q=lane&31, row=key (verified layout): each
// lane owns ONE q's scores (32 keys; partner lane+32 holds the other 32).
// Softmax: in-lane tree + ONE shfl_xor(32). P->PV A-frag: 16 cvt_pk + 8
// shfl_xor(32) (group-exchange algebra in comments) -- NO Psm, no LDS
// round-trip. PV = mfma_32x32x16(A=P, B=V) -> C col=d, row=q.
// K staged via DMA with 4-bit source pre-swizzle (c^row&15) so 32-row strided
// reads are ~2-way; V staging as r9 (c^row&7, reads ~4-way). Double-buffered,
// one barrier/tile, fused Q-RoPE, XCD remap. In-place og==qg safe.
// ---------------------------------------------------------------------------
__global__ __launch_bounds__(256, 2) void attn_kernel(
    const short* __restrict__ qg, const short* __restrict__ kg,
    const short* __restrict__ vtg, short* __restrict__ og,
    const float2* __restrict__ tab)
{
  __shared__ __align__(16) short Ksm[2 * 64 * 128];   // [buf][key][d], swz c^row&15
  __shared__ __align__(16) short Vsm[2 * 128 * 64];   // [buf][d][key], swz c^row&7

  const int t = threadIdx.x;
  const int l = t & 63;
  const int w = t >> 6;                 // 0..3
  const int l31 = l & 31;
  const int h2 = l >> 5;                // half: 0/1

  // XCD remap: lid 0..511; group g = (b,kv) 0..15; two groups per XCD.
  const int lid = blockIdx.x + 8 * (blockIdx.y + 16 * blockIdx.z);
  const int xcd = lid & 7, idx = lid >> 3;
  const int g = xcd * 2 + (idx >> 5);
  const int wv_ = idx & 31;
  const int b = g >> 2, kv = g & 3;
  const int h = kv * 4 + (wv_ >> 3);
  const int jb = wv_ & 7;

  // DMA staging (256 threads, 4 issues each, 16B/lane, linear LDS dest t*16):
  // K 64x128: issue j rows j*16+(t>>4); src seg = (t&15) ^ (row&15 = t>>4).
  // V 128x64: issue j rows j*32+(t>>3); src seg = (t&7) ^ ((t>>3)&7).
  const int krow0 = t >> 4, kseg = (t & 15) ^ (t >> 4);
  const int vrow0 = t >> 3, vseg = (t & 7) ^ ((t >> 3) & 7);

  const short* kbaseptr = kg + ((size_t)(b * 2048)) * 512 + kv * 128;
  const short* vbaseptr = vtg + ((size_t)(b * 512 + kv * 128)) * 2048;

  const float SC = 0.08838834764831845f * 1.4426950408889634f; // rsqrt(128)*log2e
  const f32x16 zero16 = {0.f,0.f,0.f,0.f,0.f,0.f,0.f,0.f,
                         0.f,0.f,0.f,0.f,0.f,0.f,0.f,0.f};

#define STAGET(c)                                                             \
  do {                                                                        \
    GLOAD_LDS16(ksrc,          Ksm + (c) * 8192 + t * 8);                     \
    GLOAD_LDS16(ksrc + 8192,   Ksm + (c) * 8192 + 2048 + t * 8);              \
    GLOAD_LDS16(ksrc + 16384,  Ksm + (c) * 8192 + 4096 + t * 8);              \
    GLOAD_LDS16(ksrc + 24576,  Ksm + (c) * 8192 + 6144 + t * 8);              \
    GLOAD_LDS16(vsrc,          Vsm + (c) * 8192 + t * 8);                     \
    GLOAD_LDS16(vsrc + 65536,  Vsm + (c) * 8192 + 2048 + t * 8);              \
    GLOAD_LDS16(vsrc + 131072, Vsm + (c) * 8192 + 4096 + t * 8);              \
    GLOAD_LDS16(vsrc + 196608, Vsm + (c) * 8192 + 6144 + t * 8);              \
    ksrc += 64 * 512;                                                         \
    vsrc += 64;                                                               \
  } while (0)

  for (int sp2 = 0; sp2 < 2; ++sp2) {
    const int jj = sp2 ? (15 - jb) : jb;
    const int qb0 = jj * 128;
    const int qw0 = qb0 + w * 32;       // wave owns 32 q rows
    const int qmaxw = qw0 + 31;
    const int ntl = 2 * jj + 2;

    const short* ksrc = kbaseptr + (size_t)krow0 * 512 + kseg * 8;
    const short* vsrc = vbaseptr + (size_t)vrow0 * 2048 + vseg * 8;

    // Q B-frags with FUSED RoPE: lane holds Q[q=qw0+l31][d=16m+8*h2+j], m 0..7.
    // RoPE pairs (d, d+64) = (qf[m], qf[m+4]); angle index d_lo = 16m+8h2+j.
    s16x8 qf[8];
    {
      const int pos = qw0 + l31;
      const short* qrow =
          qg + ((size_t)(b * 2048 + pos)) * 2048 + h * 128 + 8 * h2;
      s16x8 qr[8];
#pragma unroll
      for (int m = 0; m < 8; ++m) qr[m] = *(const s16x8*)(qrow + 16 * m);
      const float2* tb = tab + (((size_t)pos) << 6) + 8 * h2;
#pragma unroll
      for (int m = 0; m < 4; ++m) {
        float lo[8], hi[8];
#pragma unroll
        for (int j = 0; j < 8; ++j) {
          const float2 cs2 = tb[16 * m + j];
          const float l0 = bf2f(qr[m][j]);
          const float h0 = bf2f(qr[m + 4][j]);
          lo[j] = l0 * cs2.x - h0 * cs2.y;
          hi[j] = h0 * cs2.x + l0 * cs2.y;
        }
        union { unsigned int u[4]; s16x8 v; } plo, phi;
#pragma unroll
        for (int j = 0; j < 4; ++j) {
          asm("v_cvt_pk_bf16_f32 %0, %1, %2"
              : "=v"(plo.u[j]) : "v"(lo[2 * j]), "v"(lo[2 * j + 1]));
          asm("v_cvt_pk_bf16_f32 %0, %1, %2"
              : "=v"(phi.u[j]) : "v"(hi[2 * j]), "v"(hi[2 * j + 1]));
        }
        qf[m] = plo.v;
        qf[m + 4] = phi.v;
      }
    }

    f32x16 o32[4];
#pragma unroll
    for (int nb = 0; nb < 4; ++nb) o32[nb] = zero16;
    float m_i = NEGH, l_i = 0.f;      // per-lane stats for q = qw0 + l31

    STAGET(0);
    __syncthreads();
    int cur = 0;

    for (int tl = 0; tl < ntl; ++tl) {
      const int kbase = tl * 64;
      if (tl + 1 < ntl) STAGET(cur ^ 1);

      if (kbase <= qmaxw) {
        const short* Kb = Ksm + cur * 8192;
        const short* Vb = Vsm + cur * 8192;

        // QK: St[kb] C: col=q=l31, row(reg)=(reg&3)+8*(reg>>2)+4*h2 (key in blk)
        f32x16 st0 = zero16, st1 = zero16;
        __builtin_amdgcn_s_setprio(1);
#pragma unroll
        for (int m = 0; m < 8; ++m) {
          const int ch = ((2 * m + h2) ^ (l & 15)) * 8;
          const s16x8 a0 = *(const s16x8*)&Kb[l31 * 128 + ch];
          const s16x8 a1 = *(const s16x8*)&Kb[(32 + l31) * 128 + ch];
          st0 = __builtin_amdgcn_mfma_f32_32x32x16_bf16(a0, qf[m], st0, 0, 0, 0);
          st1 = __builtin_amdgcn_mfma_f32_32x32x16_bf16(a1, qf[m], st1, 0, 0, 0);
        }
        __builtin_amdgcn_s_setprio(0);

        // causal mask (raw scores; SC folded into exp2)
        const bool maskt = (kbase + 63 > qw0);
        const int qabs = qw0 + l31;
        if (maskt) {
#pragma unroll
          for (int r = 0; r < 16; ++r) {
            const int krow = (r & 3) + 8 * (r >> 2) + 4 * h2;
            if (kbase + krow > qabs) st0[r] = NEGH;
            if (kbase + 32 + krow > qabs) st1[r] = NEGH;
          }
        }
        // in-lane max over 32 + one cross-half combine
        float tm = NEGH;
#pragma unroll
        for (int r = 0; r < 16; ++r) tm = fmaxf(tm, fmaxf(st0[r], st1[r]));
        float tl_ = fmaxf(tm, __shfl_xor(tm, 32));
        const float mnew = fmaxf(m_i, tl_);
        if (!__all(tl_ <= m_i)) {       // exact skip: alpha==1 when max static
          const float alpha = exp2f((m_i - mnew) * SC);
          l_i *= alpha;
#pragma unroll
          for (int r = 0; r < 16; ++r) {
            const int qrow = (r & 3) + 8 * (r >> 2) + 4 * h2;
            const float ar = __shfl(alpha, qrow);
#pragma unroll
            for (int nb = 0; nb < 4; ++nb) o32[nb][r] *= ar;
          }
        }
        m_i = mnew;
        const float mS = mnew * SC;
        float rs = 0.f;
#pragma unroll
        for (int r = 0; r < 16; ++r) {
          st0[r] = exp2f(fmaf(st0[r], SC, -mS));
          st1[r] = exp2f(fmaf(st1[r], SC, -mS));
          rs += st0[r] + st1[r];
        }
        rs += __shfl_xor(rs, 32);
        l_i += rs;

        // pack P->bf16: W[g] (g=key>>2): g = 2a + h2 + 8kb; a = reg>>2.
        unsigned int wA[8], wB[8];
#pragma unroll
        for (int a = 0; a < 4; ++a) {
          asm("v_cvt_pk_bf16_f32 %0, %1, %2"
              : "=v"(wA[a]) : "v"(st0[4 * a]), "v"(st0[4 * a + 1]));
          asm("v_cvt_pk_bf16_f32 %0, %1, %2"
              : "=v"(wB[a]) : "v"(st0[4 * a + 2]), "v"(st0[4 * a + 3]));
          asm("v_cvt_pk_bf16_f32 %0, %1, %2"
              : "=v"(wA[a + 4]) : "v"(st1[4 * a]), "v"(st1[4 * a + 1]));
          asm("v_cvt_pk_bf16_f32 %0, %1, %2"
              : "=v"(wB[a + 4]) : "v"(st1[4 * a + 2]), "v"(st1[4 * a + 3]));
        }

        // PV: per kk (16-key slice): A-frag keys 16kk+8*h2+0..7 = groups
        // ga=4kk+2h2 (even, owned by h2=0 side), gb=ga+1 (odd, h2=1 side).
        // exchange: h2=0 sends wX[i0+1] (g=4kk+2), h2=1 sends wX[i0] (g=4kk+1),
        // where i0 = 2*(kk&1)+4*(kk>>1). frag(h2=0)=[own(i0),recv];
        // frag(h2=1)=[recv,own(i0+1)].
        __builtin_amdgcn_s_setprio(1);
#pragma unroll
        for (int kk = 0; kk < 4; ++kk) {
          const int i0 = 2 * (kk & 1) + 4 * (kk >> 1);
          const unsigned int sA = h2 ? wA[i0] : wA[i0 + 1];
          const unsigned int sB = h2 ? wB[i0] : wB[i0 + 1];
          const unsigned int rA = (unsigned int)__shfl_xor((int)sA, 32);
          const unsigned int rB = (unsigned int)__shfl_xor((int)sB, 32);
          union { unsigned int u[4]; s16x8 v; } pfu;
          pfu.u[0] = h2 ? rA : wA[i0];
          pfu.u[1] = h2 ? rB : wB[i0];
          pfu.u[2] = h2 ? wA[i0 + 1] : rA;
          pfu.u[3] = h2 ? wB[i0 + 1] : rB;
          const s16x8 pf = pfu.v;
#pragma unroll
          for (int nb = 0; nb < 4; ++nb) {
            const s16x8 vf = *(const s16x8*)&Vb[(nb * 32 + l31) * 64 +
                                                (((2 * kk + h2) ^ (l & 7)) * 8)];
            o32[nb] = __builtin_amdgcn_mfma_f32_32x32x16_bf16(pf, vf, o32[nb],
                                                              0, 0, 0);
          }
        }
        __builtin_amdgcn_s_setprio(0);
      }

      __syncthreads();                  // drains vmcnt; next buf landed
      cur ^= 1;
    }

    // store: O C-layout col=d=nb*32+l31, row(reg)=qrow; coalesced 64B runs.
#pragma unroll
    for (int r = 0; r < 16; ++r) {
      const int qrow = (r & 3) + 8 * (r >> 2) + 4 * h2;
      const float lr = __shfl(l_i, qrow);
      const float inv = 1.f / lr;
      const size_t base =
          ((size_t)(b * 2048 + qw0 + qrow)) * 2048 + h * 128 + l31;
#pragma unroll
      for (int nb = 0; nb < 4; ++nb)
        og[base + nb * 32] = f2bf(o32[nb][r] * inv);
    }
  }
#undef STAGET
}

// ---------------------------------------------------------------------------
extern "C" void kernel_launch(void* const* d_in, const int* in_sizes, int n_in,
                              void* d_out, int out_size, void* d_ws,
                              size_t ws_size, hipStream_t stream)
{
  const float* x  = (const float*)d_in[0];
  const float* wq = (const float*)d_in[1];
  const float* bq = (const float*)d_in[2];
  const float* wk = (const float*)d_in[3];
  const float* bk = (const float*)d_in[4];
  const float* wv = (const float*)d_in[5];
  const float* bv = (const float*)d_in[6];
  const float* wo = (const float*)d_in[7];
  const float* bo = (const float*)d_in[8];
  float* out = (float*)d_out;

  // ws layout (77 MiB used; ws_size >= 80 MiB):
  //   xb  @0      32 MiB  [8192][2048] bf16; dead after KV-proj -> wob reuses @0
  //   wqb @32MiB   8 MiB; wkb @40MiB 2 MiB; wvb @42MiB 2 MiB
  //   qws @44MiB  32 MiB  [8192][2048] bf16; attention output in place
  //   tab @76MiB   1 MiB  float2[2048][64] rope cos/sin
  // d_out scratch: kws @out+0 8 MiB; vtw @out+8M 8 MiB; vtmp @out+16M 8 MiB
  char* ws = (char*)d_ws;
  short* xb  = (short*)ws;
  short* wqb = (short*)(ws + (32ull << 20));
  short* wkb = (short*)(ws + (40ull << 20));
  short* wvb = (short*)(ws + (42ull << 20));
  short* qws = (short*)(ws + (44ull << 20));
  float2* tab = (float2*)(ws + (76ull << 20));
  short* wob = xb;
  short* kws = (short*)d_out;
  short* vtw = (short*)((char*)d_out + (8ull << 20));
  short* vtmp = (short*)((char*)d_out + (16ull << 20));

  const dim3 blk(256);
  cvt_kernel<<<16384, blk, 0, stream>>>(x, xb);
  wcvt_kernel<<<6656, blk, 0, stream>>>(wq, wk, wv, wqb, wkb, wvb, tab);
  gemm256_bt<<<dim3(8, 32), dim3(512), 0, stream>>>(xb, wqb, bq, qws, 8192, 2048, 2048, 0);
  gemm_bt<<<dim3(8, 64), blk, 0, stream>>>(xb, wkb, bk, bv, kws, vtmp, 8192, 1024, 2048, 3);
  trans_kernel<<<dim3(128, 8), blk, 0, stream>>>(vtmp, vtw);
  rope_kernel<<<8192, blk, 0, stream>>>(kws, 2, tab);   // K only; Q-rope fused
  cvt_kernel<<<4096, blk, 0, stream>>>(wo, wob);        // after KV-proj (xb dead)
  attn_kernel<<<dim3(8, 16, 4), blk, 0, stream>>>(qws, kws, vtw, qws, tab);
  gemm256_bt<<<dim3(8, 32), dim3(512), 0, stream>>>(qws, wob, bo, out, 8192, 2048, 2048, 1);
}